// Round 12
// baseline (371.705 us; speedup 1.0000x reference)
//
#include <hip/hip_runtime.h>
#include <math.h>

// Problem constants
constexpr int BSZ   = 16;
constexpr int NDET  = 48;
constexpr int PAIRS = NDET * (NDET - 1);      // 2256
constexpr int ROWS  = BSZ * PAIRS;            // 36096
constexpr int DF    = 2048;
constexpr int DH    = 1024;
constexpr int DE    = 512;
constexpr int EHALF = 256;
constexpr int NCLS  = 92;
constexpr int NEXT  = DE + 128;               // 640: so/re GEMM width incl. classifier cols
constexpr int LABW  = 1 + 92 + 40;            // 133

typedef __attribute__((ext_vector_type(8))) short bf16x8;   // 8 bf16 in 4 VGPRs
typedef __attribute__((ext_vector_type(4))) float f32x4;

__device__ __forceinline__ short f2bf(float f) {
    union { float f; unsigned u; } a; a.f = f;
    unsigned r = a.u + 0x7fffu + ((a.u >> 16) & 1u);   // RNE
    return (short)(r >> 16);
}
__device__ __forceinline__ float bf2f(short h) {
    union { unsigned u; float f; } x;
    x.u = ((unsigned)(unsigned short)h) << 16;
    return x.f;
}

// ---------------------------------------------------------------------------
// Merged prep. Elementwise ranges: det conv | cwt build | W3->bf16 | R2->bf16;
// then 5-job transpose (W1 top/bot, W2, W3, R2).
// ---------------------------------------------------------------------------
constexpr int N4DET = BSZ * NDET * DF / 4;    // 393216
constexpr int N4CWT = 128 * DE / 4;           // 16384
constexpr int N4W3  = DH * DE / 4;            // 131072
constexpr int N4R2  = 256 * DE / 4;           // 32768
constexpr int NCONVB = (N4DET + N4CWT + N4W3 + N4R2) / 256;   // 2240

struct TransJobs {
    const float* src[5];
    short*       dst[5];
    int K[5], N[5];
    int cum[6];
};

__global__ __launch_bounds__(256) void prep_kernel(
    const float* __restrict__ det, short* __restrict__ det_bf,
    const float* __restrict__ cw, short* __restrict__ cwt,
    const float* __restrict__ W3, short* __restrict__ W3bf,
    const float* __restrict__ R2, short* __restrict__ R2bf,
    TransJobs jobs)
{
    if (blockIdx.x < NCONVB) {
        int i = blockIdx.x * 256 + threadIdx.x;
        const float* src; short* dst; int k;
        if (i < N4DET) { src = det; dst = det_bf; k = i; }
        else if (i < N4DET + N4CWT) {
            k = i - N4DET;
            int n = (k * 4) >> 9;
            short4 o = {0, 0, 0, 0};
            if (n < NCLS) {
                float4 v = ((const float4*)cw)[k];
                o.x = f2bf(v.x); o.y = f2bf(v.y); o.z = f2bf(v.z); o.w = f2bf(v.w);
            }
            ((short4*)cwt)[k] = o;
            return;
        }
        else if (i < N4DET + N4CWT + N4W3) { src = W3; dst = W3bf; k = i - N4DET - N4CWT; }
        else { src = R2; dst = R2bf; k = i - N4DET - N4CWT - N4W3; }
        float4 v = ((const float4*)src)[k];
        short4 o;
        o.x = f2bf(v.x); o.y = f2bf(v.y); o.z = f2bf(v.z); o.w = f2bf(v.w);
        ((short4*)dst)[k] = o;
        return;
    }
    __shared__ float tile[32][33];
    int t = blockIdx.x - NCONVB;
    int j = 0;
    while (t >= jobs.cum[j + 1]) ++j;
    int lt = t - jobs.cum[j];
    int K = jobs.K[j], N = jobs.N[j];
    int nx = N >> 5;
    int ky = lt / nx, nxi = lt - ky * nx;
    int n0 = nxi * 32, k0 = ky * 32;
    const float* src = jobs.src[j];
    short* dst = jobs.dst[j];
    int tx = threadIdx.x & 31, ty = threadIdx.x >> 5;
#pragma unroll
    for (int i = ty; i < 32; i += 8)
        tile[i][tx] = src[(size_t)(k0 + i) * N + n0 + tx];
    __syncthreads();
#pragma unroll
    for (int i = ty; i < 32; i += 8)
        dst[(size_t)(n0 + i) * K + k0 + tx] = f2bf(tile[tx][i]);
}

// ---------------------------------------------------------------------------
// MFMA GEMM (BK=64 as two 128x32 halves; R9-verified).
// R12: the memory-ish re job (K=256) now rides WITH the h2 launch (DUAL on
// bx) to fill h2's idle memory pipe (h2 was 19% HBM / 36% MFMA); the so
// launch runs pure. Dependency-safe: rh exists before h2; re_ext consumed
// after so.
// ---------------------------------------------------------------------------
__device__ __forceinline__ void load16_lds(const void* g, void* l) {
    __builtin_amdgcn_global_load_lds(
        (const __attribute__((address_space(1))) unsigned int*)g,
        (__attribute__((address_space(3))) unsigned int*)l, 16, 0, 0);
}

template <bool BIAS, bool RELU, bool OUTBF16, bool SWIZZLE, bool DUAL>
__global__ __launch_bounds__(256, 4) void mfma_gemm(
    const short* __restrict__ A, const short* __restrict__ Bt,
    const float* __restrict__ bias, void* __restrict__ C,
    int M, int N, int K, int lda, int ldb,
    const short* A2, const short* Bt2, void* C2, int nsplit,
    int K2, int lda2, int ldb2, int N2)
{
    __shared__ __align__(16) char smem_raw[32768];   // As 16KB | Bs 16KB
    short* As = (short*)smem_raw;
    short* Bs = As + 128 * 64;

    int bx, by;
    if (SWIZZLE) {
        int nb  = gridDim.x;
        int gid = blockIdx.y * nb + blockIdx.x;
        int xcd = gid & 7;
        int j   = gid >> 3;
        int rows_per = gridDim.y >> 3;
        int lr  = j / nb;
        bx = j - lr * nb;
        by = xcd * rows_per + lr;
    } else {
        bx = blockIdx.x; by = blockIdx.y;
    }
    bool second = DUAL && (bx >= nsplit);
    bool dobias = BIAS && !second;               // bias/relu apply to job1 only
    if (second) {
        bx -= nsplit; A = A2; Bt = Bt2; C = C2;
        K = K2; lda = lda2; ldb = ldb2; N = N2;
    }
    if (by * 128 >= M) return;                      // padded tail

    const int tid  = threadIdx.x;
    const int wave = tid >> 6;
    const int lane = tid & 63;
    const int m0 = by * 128;
    const int n0 = bx * 128;
    const int wm = (wave & 1) * 64;
    const int wn = (wave >> 1) * 64;

    f32x4 acc[4][4] = {};

    const int q  = lane >> 4;
    const int lm = lane & 15;

    for (int k0 = 0; k0 < K; k0 += 64) {
#pragma unroll
        for (int it = 0; it < 4; ++it) {
            int c    = (it & 1) * 256 + tid;
            int half = it >> 1;
            int row  = c >> 2;
            int kk   = (c & 3) * 8 + half * 32;
            int ldsc = half * 4096 + ((it & 1) * 256 + wave * 64) * 8;
            int gm = m0 + row; if (gm >= M) gm = M - 1;
            load16_lds(A + (size_t)gm * lda + k0 + kk, As + ldsc);
            int gn = n0 + row;                       // N%128==0: no tail
            load16_lds(Bt + (size_t)gn * ldb + k0 + kk, Bs + ldsc);
        }
        __syncthreads();

#pragma unroll
        for (int half = 0; half < 2; ++half) {
            const short* Ah = As + half * 4096;
            const short* Bh = Bs + half * 4096;
            bf16x8 af[4], bfr[4];
#pragma unroll
            for (int t = 0; t < 4; ++t) {
                af[t]  = *(const bf16x8*)(Ah + (wm + t * 16 + lm) * 32 + q * 8);
                bfr[t] = *(const bf16x8*)(Bh + (wn + t * 16 + lm) * 32 + q * 8);
            }
#pragma unroll
            for (int tm = 0; tm < 4; ++tm)
#pragma unroll
                for (int tn = 0; tn < 4; ++tn)
                    acc[tm][tn] = __builtin_amdgcn_mfma_f32_16x16x32_bf16(
                        af[tm], bfr[tn], acc[tm][tn], 0, 0, 0);
        }
        __syncthreads();
    }

    // C/D layout: col=lane&15, row=(lane>>4)*4+reg (m89-verified)
    if (OUTBF16) {
        float* scratch = (float*)smem_raw + wave * (16 * 68);
#pragma unroll
        for (int tm = 0; tm < 4; ++tm) {
            __syncthreads();
#pragma unroll
            for (int tn = 0; tn < 4; ++tn) {
                float bv = dobias ? bias[n0 + wn + tn * 16 + lm] : 0.0f;
#pragma unroll
                for (int r = 0; r < 4; ++r) {
                    float v = acc[tm][tn][r] + bv;
                    if (RELU) { if (!second) v = fmaxf(v, 0.0f); }
                    scratch[(q * 4 + r) * 68 + tn * 16 + lm] = v;
                }
            }
            __syncthreads();
#pragma unroll
            for (int p = 0; p < 2; ++p) {
                int row16 = (lane >> 3) + p * 8;
                int c0 = (lane & 7) * 8;
                float4 v0 = *(float4*)&scratch[row16 * 68 + c0];
                float4 v1 = *(float4*)&scratch[row16 * 68 + c0 + 4];
                bf16x8 o;
                o[0] = f2bf(v0.x); o[1] = f2bf(v0.y); o[2] = f2bf(v0.z); o[3] = f2bf(v0.w);
                o[4] = f2bf(v1.x); o[5] = f2bf(v1.y); o[6] = f2bf(v1.z); o[7] = f2bf(v1.w);
                int grow = m0 + wm + tm * 16 + row16;
                if (grow < M)
                    *(bf16x8*)((short*)C + (size_t)grow * N + n0 + wn + c0) = o;
            }
        }
    } else {
#pragma unroll
        for (int tm = 0; tm < 4; ++tm)
#pragma unroll
            for (int tn = 0; tn < 4; ++tn) {
                int col = n0 + wn + tn * 16 + lm;
#pragma unroll
                for (int r = 0; r < 4; ++r) {
                    int row = m0 + wm + tm * 16 + q * 4 + r;
                    if (row < M) {
                        float v = acc[tm][tn][r];
                        if (BIAS) v += bias[col];
                        if (RELU) v = fmaxf(v, 0.0f);
                        ((float*)C)[(size_t)row * N + col] = v;
                    }
                }
            }
    }
}

// ---------------------------------------------------------------------------
// Multi-job GEMM (up to 4 independent bf16-out jobs, flat 1-D grid).
// ---------------------------------------------------------------------------
struct GemmJobs {
    const short* A[4]; const short* Bt[4]; short* C[4];
    int M[4], N[4], K[4], lda[4], ldb[4];
    int cum[5];
};

__global__ __launch_bounds__(256, 4) void mfma_gemm_multi(GemmJobs jobs)
{
    __shared__ __align__(16) char smem_raw[32768];
    short* As = (short*)smem_raw;
    short* Bs = As + 128 * 64;

    int bid = blockIdx.x;
    int j = 0;
    while (bid >= jobs.cum[j + 1]) ++j;             // <=4, block-uniform
    int lt = bid - jobs.cum[j];
    const short* A  = jobs.A[j];
    const short* Bt = jobs.Bt[j];
    short* C = jobs.C[j];
    int M = jobs.M[j], N = jobs.N[j], K = jobs.K[j];
    int lda = jobs.lda[j], ldb = jobs.ldb[j];
    int ncols = N >> 7;
    int by = lt / ncols;
    int bx = lt - by * ncols;

    const int tid  = threadIdx.x;
    const int wave = tid >> 6;
    const int lane = tid & 63;
    const int m0 = by * 128;
    const int n0 = bx * 128;
    const int wm = (wave & 1) * 64;
    const int wn = (wave >> 1) * 64;

    f32x4 acc[4][4] = {};
    const int q  = lane >> 4;
    const int lm = lane & 15;

    for (int k0 = 0; k0 < K; k0 += 64) {
#pragma unroll
        for (int it = 0; it < 4; ++it) {
            int c    = (it & 1) * 256 + tid;
            int half = it >> 1;
            int row  = c >> 2;
            int kk   = (c & 3) * 8 + half * 32;
            int ldsc = half * 4096 + ((it & 1) * 256 + wave * 64) * 8;
            int gm = m0 + row; if (gm >= M) gm = M - 1;
            load16_lds(A + (size_t)gm * lda + k0 + kk, As + ldsc);
            load16_lds(Bt + (size_t)(n0 + row) * ldb + k0 + kk, Bs + ldsc);
        }
        __syncthreads();
#pragma unroll
        for (int half = 0; half < 2; ++half) {
            const short* Ah = As + half * 4096;
            const short* Bh = Bs + half * 4096;
            bf16x8 af[4], bfr[4];
#pragma unroll
            for (int t = 0; t < 4; ++t) {
                af[t]  = *(const bf16x8*)(Ah + (wm + t * 16 + lm) * 32 + q * 8);
                bfr[t] = *(const bf16x8*)(Bh + (wn + t * 16 + lm) * 32 + q * 8);
            }
#pragma unroll
            for (int tm = 0; tm < 4; ++tm)
#pragma unroll
                for (int tn = 0; tn < 4; ++tn)
                    acc[tm][tn] = __builtin_amdgcn_mfma_f32_16x16x32_bf16(
                        af[tm], bfr[tn], acc[tm][tn], 0, 0, 0);
        }
        __syncthreads();
    }

    float* scratch = (float*)smem_raw + wave * (16 * 68);
#pragma unroll
    for (int tm = 0; tm < 4; ++tm) {
        __syncthreads();
#pragma unroll
        for (int tn = 0; tn < 4; ++tn)
#pragma unroll
            for (int r = 0; r < 4; ++r)
                scratch[(q * 4 + r) * 68 + tn * 16 + lm] = acc[tm][tn][r];
        __syncthreads();
#pragma unroll
        for (int p = 0; p < 2; ++p) {
            int row16 = (lane >> 3) + p * 8;
            int c0 = (lane & 7) * 8;
            float4 v0 = *(float4*)&scratch[row16 * 68 + c0];
            float4 v1 = *(float4*)&scratch[row16 * 68 + c0 + 4];
            bf16x8 o;
            o[0] = f2bf(v0.x); o[1] = f2bf(v0.y); o[2] = f2bf(v0.z); o[3] = f2bf(v0.w);
            o[4] = f2bf(v1.x); o[5] = f2bf(v1.y); o[6] = f2bf(v1.z); o[7] = f2bf(v1.w);
            int grow = m0 + wm + tm * 16 + row16;
            if (grow < M)
                *(bf16x8*)(C + (size_t)grow * N + n0 + wn + c0) = o;
        }
    }
}

// ---------------------------------------------------------------------------
// UV merge (in-place): UVa = UVa + UVb + b1 (U-half cols only).
// ---------------------------------------------------------------------------
constexpr int N4UV = BSZ * NDET * 2048 / 4;   // 393216 short4s
__global__ __launch_bounds__(256) void uvmerge_kernel(
    short* __restrict__ UVa, const short* __restrict__ UVb,
    const float* __restrict__ b1)
{
    int i = blockIdx.x * 256 + threadIdx.x;
    if (i >= N4UV) return;
    short4 a = ((const short4*)UVa)[i];
    short4 b = ((const short4*)UVb)[i];
    int col4 = i & 511;
    float4 bb = {0.0f, 0.0f, 0.0f, 0.0f};
    if (col4 < 256) bb = ((const float4*)b1)[col4];
    short4 o;
    o.x = f2bf(bf2f(a.x) + bf2f(b.x) + bb.x);
    o.y = f2bf(bf2f(a.y) + bf2f(b.y) + bb.y);
    o.z = f2bf(bf2f(a.z) + bf2f(b.z) + bb.z);
    o.w = f2bf(bf2f(a.w) + bf2f(b.w) + bb.w);
    ((short4*)UVa)[i] = o;
}

// ---------------------------------------------------------------------------
// Fused pairs + rh: wave-per-row.
// ---------------------------------------------------------------------------
__global__ __launch_bounds__(256) void pairs_rh_kernel(
    const short* __restrict__ UVs,
    const int* __restrict__ sids, const int* __restrict__ oids,
    short* __restrict__ h1,
    const float* __restrict__ rp, const float* __restrict__ R1,
    const float* __restrict__ rb1, short* __restrict__ rh, int b0)
{
    int wave = threadIdx.x >> 6, lane = threadIdx.x & 63;
    int r = blockIdx.x * 4 + wave;
    int b = b0 + r / PAIRS;
    int p = r % PAIRS;

    const bf16x8* us = (const bf16x8*)(UVs + (size_t)(b * NDET + sids[p]) * 2048);
    const bf16x8* uo = (const bf16x8*)(UVs + (size_t)(b * NDET + oids[p]) * 2048 + 1024);
    bf16x8* hrow = (bf16x8*)(h1 + (size_t)r * DH);
#pragma unroll
    for (int i = 0; i < 2; ++i) {
        int idx = lane + i * 64;            // 128 bf16x8 per 1024-elem row
        bf16x8 a = us[idx], c = uo[idx];
        bf16x8 h;
#pragma unroll
        for (int e = 0; e < 8; ++e)
            h[e] = f2bf(fmaxf(bf2f(a[e]) + bf2f(c[e]), 0.0f));
        hrow[idx] = h;
    }

    int rg = b0 * PAIRS + r;
    const float* rowp = rp + (size_t)rg * 12;
    float4 acc = ((const float4*)rb1)[lane];
#pragma unroll
    for (int k = 0; k < 12; ++k) {
        float rv = rowp[k];
        float4 w = ((const float4*)(R1 + k * 256))[lane];
        acc.x = fmaf(rv, w.x, acc.x);
        acc.y = fmaf(rv, w.y, acc.y);
        acc.z = fmaf(rv, w.z, acc.z);
        acc.w = fmaf(rv, w.w, acc.w);
    }
    short4 o;
    o.x = f2bf(fmaxf(acc.x, 0.0f));
    o.y = f2bf(fmaxf(acc.y, 0.0f));
    o.z = f2bf(fmaxf(acc.z, 0.0f));
    o.w = f2bf(fmaxf(acc.w, 0.0f));
    ((short4*)(rh + (size_t)r * 256))[lane] = o;
}

// ---------------------------------------------------------------------------
// Fused row_prep + focal: wave-per-row (logits from extended GEMM columns;
// ||comb||^2 = 2 + 2*rho/(||so||*||re||)).
// ---------------------------------------------------------------------------
__global__ __launch_bounds__(256) void rowprep_focal_kernel(
    const short* __restrict__ so_ext, const short* __restrict__ re_ext,
    const float* __restrict__ traj, const float* __restrict__ temperature,
    const int* __restrict__ sids, const int* __restrict__ oids,
    const int* __restrict__ labels,
    float4* __restrict__ pn, float* __restrict__ dist_arr, int b0)
{
    int wave = threadIdx.x >> 6, lane = threadIdx.x & 63;
    int r = blockIdx.x * 4 + wave;
    int rg = b0 * PAIRS + r;
    int b = b0 + r / PAIRS;
    int p = r % PAIRS;

    const short* srow = so_ext + (size_t)r * NEXT;
    const short* rrow = re_ext + (size_t)r * NEXT;
    bf16x8 sv = *(const bf16x8*)(srow + lane * 8);
    bf16x8 uv = *(const bf16x8*)(rrow + lane * 8);
    float s[8], u[8];
#pragma unroll
    for (int i = 0; i < 8; ++i) { s[i] = bf2f(sv[i]); u[i] = bf2f(uv[i]); }

    const float* tsrc = (lane < 32)
        ? (traj + (size_t)(b * NDET + sids[p]) * EHALF + lane * 8)
        : (traj + (size_t)(b * NDET + oids[p]) * EHALF + (lane - 32) * 8);
    float4 t0 = ((const float4*)tsrc)[0], t1 = ((const float4*)tsrc)[1];
    float t[8] = {t0.x, t0.y, t0.z, t0.w, t1.x, t1.y, t1.z, t1.w};

    float ss = 0.0f, sr = 0.0f, rho = 0.0f, sd = 0.0f;
#pragma unroll
    for (int i = 0; i < 8; ++i) {
        ss  += s[i] * s[i];
        sr  += u[i] * u[i];
        rho += s[i] * u[i];
        sd  += fabsf(t[i] - s[i]);
    }
#pragma unroll
    for (int m = 1; m < 64; m <<= 1) {
        ss  += __shfl_xor(ss, m);
        sr  += __shfl_xor(sr, m);
        rho += __shfl_xor(rho, m);
        sd  += __shfl_xor(sd, m);
    }
    float inv_s = 1.0f / fmaxf(sqrtf(ss), 1e-12f);
    float inv_r = 1.0f / fmaxf(sqrtf(sr), 1e-12f);
    float ncomb = sqrtf(fmaxf(2.0f + 2.0f * rho * inv_s * inv_r, 0.0f));
    float scale = 1.0f / (fmaxf(ncomb, 1e-12f) * temperature[0]);

    float flp = 0.0f, fln = 0.0f, fm = 0.0f;
    size_t labbase = (size_t)rg * LABW;
#pragma unroll
    for (int h = 0; h < 2; ++h) {
        int c = lane + h * 64;
        if (c < NCLS) {
            float l = (bf2f(srow[DE + c]) * inv_s + bf2f(rrow[DE + c]) * inv_r) * scale;
            int tl = labels[labbase + 1 + c];
            if (tl > 0) fm = 1.0f;
            float tf = (float)tl;
            float pr = 1.0f / (1.0f + expf(-l));
            float lg = log1pf(expf(-fabsf(l)));
            float ce = fmaxf(l, 0.0f) - l * tf + lg;
            float pt = pr * tf + (1.0f - pr) * (1.0f - tf);
            float om = 1.0f - pt;
            float at = 0.25f * tf + 0.75f * (1.0f - tf);
            flp += at * ce * om * om;
            float ce0 = fmaxf(l, 0.0f) + lg;
            fln += 0.75f * ce0 * pr * pr;
        }
    }
#pragma unroll
    for (int m = 1; m < 64; m <<= 1) {
        flp += __shfl_xor(flp, m);
        fln += __shfl_xor(fln, m);
        fm  += __shfl_xor(fm, m);
    }
    if (lane == 0) {
        int posf = (fm > 0.5f) ? 1 : 0;
        int negf = (labels[labbase] > 0) ? 1 : 0;
        pn[rg] = make_float4(posf ? flp : 0.0f, negf ? fln : 0.0f, 0.0f,
                             (float)(posf + 2 * negf));
        dist_arr[rg] = sd;
    }
}

// ---------------------------------------------------------------------------
// Two-stage final reduce.
// ---------------------------------------------------------------------------
struct RedRec { double sp, sn, sd; int cp, cn; };
constexpr int RED1 = 64;
constexpr int ROWS_PER_RED = ROWS / RED1;           // 564

__global__ __launch_bounds__(256) void reduce1_kernel(
    const float4* __restrict__ pn, const float* __restrict__ dist_arr,
    RedRec* __restrict__ scratch)
{
    int tid = threadIdx.x;
    int base = blockIdx.x * ROWS_PER_RED;
    double sp = 0.0, sn = 0.0, sd = 0.0;
    int cp = 0, cn = 0;
    for (int i = tid; i < ROWS_PER_RED; i += 256) {
        float4 v = pn[base + i];
        sp += (double)v.x; sn += (double)v.y; sd += (double)dist_arr[base + i];
        int f = (int)v.w;
        cp += f & 1; cn += (f >> 1) & 1;
    }
    __shared__ double A[256], B[256], C[256];
    __shared__ int I[256], J[256];
    A[tid] = sp; B[tid] = sn; C[tid] = sd; I[tid] = cp; J[tid] = cn;
    __syncthreads();
    for (int st = 128; st > 0; st >>= 1) {
        if (tid < st) { A[tid] += A[tid + st]; B[tid] += B[tid + st]; C[tid] += C[tid + st];
                        I[tid] += I[tid + st]; J[tid] += J[tid + st]; }
        __syncthreads();
    }
    if (tid == 0) {
        RedRec rec; rec.sp = A[0]; rec.sn = B[0]; rec.sd = C[0];
        rec.cp = I[0]; rec.cn = J[0];
        scratch[blockIdx.x] = rec;
    }
}

__global__ __launch_bounds__(64) void reduce2_kernel(
    const RedRec* __restrict__ scratch, float* __restrict__ out)
{
    int lane = threadIdx.x;
    RedRec rec = scratch[lane];
    double sp = rec.sp, sn = rec.sn, sd = rec.sd;
    int cp = rec.cp, cn = rec.cn;
#pragma unroll
    for (int m = 1; m < 64; m <<= 1) {
        sp += __shfl_xor(sp, m);
        sn += __shfl_xor(sn, m);
        sd += __shfl_xor(sd, m);
        cp += __shfl_xor(cp, m);
        cn += __shfl_xor(cn, m);
    }
    if (lane == 0) {
        int cpv = cp < 1 ? 1 : cp;
        int cnv = cn < 1 ? 1 : cn;
        out[0] = (float)(sp / ((double)cpv * NCLS) +
                         sn / ((double)cnv * NCLS) +
                         sd / ((double)ROWS * DE));
    }
}

static inline int pad8(int x) { return (x + 7) & ~7; }

extern "C" void kernel_launch(void* const* d_in, const int* in_sizes, int n_in,
                              void* d_out, int out_size, void* d_ws, size_t ws_size,
                              hipStream_t stream)
{
    const float* det    = (const float*)d_in[0];
    const float* traj   = (const float*)d_in[1];
    const float* relpos = (const float*)d_in[2];
    const float* cw     = (const float*)d_in[3];
    const float* W1     = (const float*)d_in[4];
    const float* b1     = (const float*)d_in[5];
    const float* W2     = (const float*)d_in[6];
    const float* b2     = (const float*)d_in[7];
    const float* W3     = (const float*)d_in[8];
    const float* R1     = (const float*)d_in[9];
    const float* rb1    = (const float*)d_in[10];
    const float* R2     = (const float*)d_in[11];
    const float* temp   = (const float*)d_in[12];
    const int*   labels = (const int*)d_in[13];
    const int*   sids   = (const int*)d_in[14];
    const int*   oids   = (const int*)d_in[15];
    float* out = (float*)d_out;

    // ---- Workspace carve --------------------------------------------------
    char* ws = (char*)d_ws;
    size_t off = 0;
    auto carve = [&](size_t bytes) -> char* {
        char* p = ws + off;
        off = (off + bytes + 255) & ~(size_t)255;
        return p;
    };
    float4* pn       = (float4*)carve((size_t)ROWS * 16);
    float*  dist_arr = (float*)carve((size_t)ROWS * 4);
    short*  det_bf   = (short*)carve((size_t)BSZ * NDET * DF * 2);
    short*  W1t      = (short*)carve((size_t)2048 * 2048 * 2);
    short*  W2t      = (short*)carve((size_t)DH * DH * 2);
    short*  W3t      = (short*)carve((size_t)NEXT * DH * 2);      // [640][1024]
    short*  R2t      = (short*)carve((size_t)NEXT * 256 * 2);     // [640][256]
    short*  cwt      = (short*)carve((size_t)128 * DE * 2);
    short*  W3bf     = (short*)carve((size_t)DH * DE * 2);
    short*  R2bf     = (short*)carve((size_t)256 * DE * 2);
    short*  UVa      = (short*)carve((size_t)BSZ * NDET * 2048 * 2);
    short*  UVb      = (short*)carve((size_t)BSZ * NDET * 2048 * 2);
    RedRec* red_scratch = (RedRec*)carve((size_t)RED1 * sizeof(RedRec));
    size_t fixed_off = off;

    int b_ch = 1;
    for (int cand : {16, 8, 4, 2, 1}) {
        size_t rows  = (size_t)cand * PAIRS;
        size_t bytes = fixed_off + rows * 2048 + 256 + rows * 2048 + 256
                     + rows * 512 + 256 + rows * 1280 + 256;
        if (bytes <= ws_size) { b_ch = cand; break; }
    }
    const int chunk_rows = b_ch * PAIRS;
    const int n_chunks = BSZ / b_ch;
    char* reg1 = carve((size_t)chunk_rows * 2048);
    char* reg2 = carve((size_t)chunk_rows * 2048);
    char* reg3 = carve((size_t)chunk_rows * 512);
    char* reg4 = carve((size_t)chunk_rows * 1280);

    short* h1     = (short*)reg1;
    short* h2     = (short*)reg2;
    short* so_ext = (short*)reg1;     // overwrites h1 (dead after h2 GEMM)
    short* rh     = (short*)reg3;
    short* re_ext = (short*)reg4;     // own region (R10 race fix)

    // ---- Prep (1 launch) --------------------------------------------------
    TransJobs tj;
    tj.src[0] = W1;                    tj.dst[0] = W1t;                   tj.K[0] = DF;  tj.N[0] = DH;
    tj.src[1] = W1 + (size_t)DF * DH;  tj.dst[1] = W1t + (size_t)DH * DF; tj.K[1] = DF;  tj.N[1] = DH;
    tj.src[2] = W2;                    tj.dst[2] = W2t;                   tj.K[2] = DH;  tj.N[2] = DH;
    tj.src[3] = W3;                    tj.dst[3] = W3t;                   tj.K[3] = DH;  tj.N[3] = DE;
    tj.src[4] = R2;                    tj.dst[4] = R2t;                   tj.K[4] = 256; tj.N[4] = DE;
    tj.cum[0] = 0;
    for (int i = 0; i < 5; ++i)
        tj.cum[i + 1] = tj.cum[i] + (tj.K[i] / 32) * (tj.N[i] / 32);
    prep_kernel<<<NCONVB + tj.cum[5], 256, 0, stream>>>(
        det, det_bf, cw, cwt, W3, W3bf, R2, R2bf, tj);

    // One multi-job GEMM launch: UV split-K halves + classifier projections.
    GemmJobs gj;
    gj.A[0] = det_bf;        gj.Bt[0] = W1t;        gj.C[0] = UVa;
    gj.M[0] = BSZ * NDET;    gj.N[0] = 2048;        gj.K[0] = 1024;
    gj.lda[0] = 2048;        gj.ldb[0] = 2048;
    gj.A[1] = det_bf + 1024; gj.Bt[1] = W1t + 1024; gj.C[1] = UVb;
    gj.M[1] = BSZ * NDET;    gj.N[1] = 2048;        gj.K[1] = 1024;
    gj.lda[1] = 2048;        gj.ldb[1] = 2048;
    gj.A[2] = cwt;           gj.Bt[2] = W3bf;       gj.C[2] = W3t + (size_t)512 * DH;
    gj.M[2] = 128;           gj.N[2] = 1024;        gj.K[2] = 512;
    gj.lda[2] = 512;         gj.ldb[2] = 512;
    gj.A[3] = cwt;           gj.Bt[3] = R2bf;       gj.C[3] = R2t + (size_t)512 * 256;
    gj.M[3] = 128;           gj.N[3] = 256;         gj.K[3] = 512;
    gj.lda[3] = 512;         gj.ldb[3] = 512;
    gj.cum[0] = 0;
    for (int i = 0; i < 4; ++i)
        gj.cum[i + 1] = gj.cum[i] + (gj.N[i] / 128) * ((gj.M[i] + 127) / 128);
    mfma_gemm_multi<<<gj.cum[4], 256, 0, stream>>>(gj);   // 202 blocks

    // Merge: UVa += UVb + b1 (in-place)
    uvmerge_kernel<<<(N4UV + 255) / 256, 256, 0, stream>>>(UVa, UVb, b1);

    const int mg  = (chunk_rows + 127) / 128;
    const int mgp = pad8(mg);

    for (int c = 0; c < n_chunks; ++c) {
        int b0 = c * b_ch;

        pairs_rh_kernel<<<chunk_rows / 4, 256, 0, stream>>>(
            UVa, sids, oids, h1, relpos, R1, rb1, rh, b0);

        // h2 = bf16(relu(h1 @ W2 + b2))  PLUS  re_ext = bf16(rh @ R2ext):
        // one DUAL launch (8 h2-cols + 5 re-cols). re's memory-bound blocks
        // fill h2's idle memory pipe (h2 was 19% HBM / 36% MFMA).
        mfma_gemm<true, true, true, true, true>
            <<<dim3(13, mgp), 256, 0, stream>>>(
            h1, W2t, b2, h2, chunk_rows, DH, DH, DH, DH,
            rh, R2t, re_ext, 8, 256, 256, 256, NEXT);

        // so_ext = bf16(h2 @ [W3 | W3·cw^T])   (pure, 5 cols)
        mfma_gemm<false, false, true, true, false>
            <<<dim3(5, mgp), 256, 0, stream>>>(
            h2, W3t, nullptr, so_ext, chunk_rows, NEXT, DH, DH, DH,
            nullptr, nullptr, nullptr, 0, 0, 0, 0, 0);

        rowprep_focal_kernel<<<chunk_rows / 4, 256, 0, stream>>>(
            so_ext, re_ext, traj, temp, sids, oids, labels, pn, dist_arr, b0);
    }

    reduce1_kernel<<<RED1, 256, 0, stream>>>(pn, dist_arr, red_scratch);
    reduce2_kernel<<<1, 64, 0, stream>>>(red_scratch, out);
}

// Round 13
// 364.556 us; speedup vs baseline: 1.0196x; 1.0196x over previous
//
#include <hip/hip_runtime.h>
#include <math.h>

// Problem constants
constexpr int BSZ   = 16;
constexpr int NDET  = 48;
constexpr int PAIRS = NDET * (NDET - 1);      // 2256
constexpr int ROWS  = BSZ * PAIRS;            // 36096
constexpr int DF    = 2048;
constexpr int DH    = 1024;
constexpr int DE    = 512;
constexpr int EHALF = 256;
constexpr int NCLS  = 92;
constexpr int NEXT  = DE + 128;               // 640: so/re GEMM width incl. classifier cols
constexpr int LABW  = 1 + 92 + 40;            // 133

typedef __attribute__((ext_vector_type(8))) short bf16x8;   // 8 bf16 in 4 VGPRs
typedef __attribute__((ext_vector_type(4))) float f32x4;

__device__ __forceinline__ short f2bf(float f) {
    union { float f; unsigned u; } a; a.f = f;
    unsigned r = a.u + 0x7fffu + ((a.u >> 16) & 1u);   // RNE
    return (short)(r >> 16);
}
__device__ __forceinline__ float bf2f(short h) {
    union { unsigned u; float f; } x;
    x.u = ((unsigned)(unsigned short)h) << 16;
    return x.f;
}

// ---------------------------------------------------------------------------
// Merged prep. Elementwise ranges: det conv | cwt build | W3->bf16 | R2->bf16;
// then 5-job transpose (W1 top/bot, W2, W3, R2).
// ---------------------------------------------------------------------------
constexpr int N4DET = BSZ * NDET * DF / 4;    // 393216
constexpr int N4CWT = 128 * DE / 4;           // 16384
constexpr int N4W3  = DH * DE / 4;            // 131072
constexpr int N4R2  = 256 * DE / 4;           // 32768
constexpr int NCONVB = (N4DET + N4CWT + N4W3 + N4R2) / 256;   // 2240

struct TransJobs {
    const float* src[5];
    short*       dst[5];
    int K[5], N[5];
    int cum[6];
};

__global__ __launch_bounds__(256) void prep_kernel(
    const float* __restrict__ det, short* __restrict__ det_bf,
    const float* __restrict__ cw, short* __restrict__ cwt,
    const float* __restrict__ W3, short* __restrict__ W3bf,
    const float* __restrict__ R2, short* __restrict__ R2bf,
    TransJobs jobs)
{
    if (blockIdx.x < NCONVB) {
        int i = blockIdx.x * 256 + threadIdx.x;
        const float* src; short* dst; int k;
        if (i < N4DET) { src = det; dst = det_bf; k = i; }
        else if (i < N4DET + N4CWT) {
            k = i - N4DET;
            int n = (k * 4) >> 9;
            short4 o = {0, 0, 0, 0};
            if (n < NCLS) {
                float4 v = ((const float4*)cw)[k];
                o.x = f2bf(v.x); o.y = f2bf(v.y); o.z = f2bf(v.z); o.w = f2bf(v.w);
            }
            ((short4*)cwt)[k] = o;
            return;
        }
        else if (i < N4DET + N4CWT + N4W3) { src = W3; dst = W3bf; k = i - N4DET - N4CWT; }
        else { src = R2; dst = R2bf; k = i - N4DET - N4CWT - N4W3; }
        float4 v = ((const float4*)src)[k];
        short4 o;
        o.x = f2bf(v.x); o.y = f2bf(v.y); o.z = f2bf(v.z); o.w = f2bf(v.w);
        ((short4*)dst)[k] = o;
        return;
    }
    __shared__ float tile[32][33];
    int t = blockIdx.x - NCONVB;
    int j = 0;
    while (t >= jobs.cum[j + 1]) ++j;
    int lt = t - jobs.cum[j];
    int K = jobs.K[j], N = jobs.N[j];
    int nx = N >> 5;
    int ky = lt / nx, nxi = lt - ky * nx;
    int n0 = nxi * 32, k0 = ky * 32;
    const float* src = jobs.src[j];
    short* dst = jobs.dst[j];
    int tx = threadIdx.x & 31, ty = threadIdx.x >> 5;
#pragma unroll
    for (int i = ty; i < 32; i += 8)
        tile[i][tx] = src[(size_t)(k0 + i) * N + n0 + tx];
    __syncthreads();
#pragma unroll
    for (int i = ty; i < 32; i += 8)
        dst[(size_t)(n0 + i) * K + k0 + tx] = f2bf(tile[tx][i]);
}

// ---------------------------------------------------------------------------
// MFMA GEMM (BK=64 as two 128x32 halves; R9-verified). R13 = R11 config:
// so (K=1024) + re (K=256) share the DUAL launch (R12's h2+re pairing was
// neutral-negative — two jobs in one launch share the memory subsystem;
// the 5:1 so:re block ratio hides re in so's shadow better).
// ---------------------------------------------------------------------------
__device__ __forceinline__ void load16_lds(const void* g, void* l) {
    __builtin_amdgcn_global_load_lds(
        (const __attribute__((address_space(1))) unsigned int*)g,
        (__attribute__((address_space(3))) unsigned int*)l, 16, 0, 0);
}

template <bool BIAS, bool RELU, bool OUTBF16, bool SWIZZLE, bool DUAL>
__global__ __launch_bounds__(256, 4) void mfma_gemm(
    const short* __restrict__ A, const short* __restrict__ Bt,
    const float* __restrict__ bias, void* __restrict__ C,
    int M, int N, int K, int lda, int ldb,
    const short* A2, const short* Bt2, void* C2, int nsplit,
    int K2, int lda2, int ldb2, int N2)
{
    __shared__ __align__(16) char smem_raw[32768];   // As 16KB | Bs 16KB
    short* As = (short*)smem_raw;
    short* Bs = As + 128 * 64;

    int bx, by;
    if (SWIZZLE) {
        int nb  = gridDim.x;
        int gid = blockIdx.y * nb + blockIdx.x;
        int xcd = gid & 7;
        int j   = gid >> 3;
        int rows_per = gridDim.y >> 3;
        int lr  = j / nb;
        bx = j - lr * nb;
        by = xcd * rows_per + lr;
    } else {
        bx = blockIdx.x; by = blockIdx.y;
    }
    if (DUAL && bx >= nsplit) {
        bx -= nsplit; A = A2; Bt = Bt2; C = C2;
        K = K2; lda = lda2; ldb = ldb2; N = N2;
    }
    if (by * 128 >= M) return;                      // padded tail

    const int tid  = threadIdx.x;
    const int wave = tid >> 6;
    const int lane = tid & 63;
    const int m0 = by * 128;
    const int n0 = bx * 128;
    const int wm = (wave & 1) * 64;
    const int wn = (wave >> 1) * 64;

    f32x4 acc[4][4] = {};

    const int q  = lane >> 4;
    const int lm = lane & 15;

    for (int k0 = 0; k0 < K; k0 += 64) {
#pragma unroll
        for (int it = 0; it < 4; ++it) {
            int c    = (it & 1) * 256 + tid;
            int half = it >> 1;
            int row  = c >> 2;
            int kk   = (c & 3) * 8 + half * 32;
            int ldsc = half * 4096 + ((it & 1) * 256 + wave * 64) * 8;
            int gm = m0 + row; if (gm >= M) gm = M - 1;
            load16_lds(A + (size_t)gm * lda + k0 + kk, As + ldsc);
            int gn = n0 + row;                       // N%128==0: no tail
            load16_lds(Bt + (size_t)gn * ldb + k0 + kk, Bs + ldsc);
        }
        __syncthreads();

#pragma unroll
        for (int half = 0; half < 2; ++half) {
            const short* Ah = As + half * 4096;
            const short* Bh = Bs + half * 4096;
            bf16x8 af[4], bfr[4];
#pragma unroll
            for (int t = 0; t < 4; ++t) {
                af[t]  = *(const bf16x8*)(Ah + (wm + t * 16 + lm) * 32 + q * 8);
                bfr[t] = *(const bf16x8*)(Bh + (wn + t * 16 + lm) * 32 + q * 8);
            }
#pragma unroll
            for (int tm = 0; tm < 4; ++tm)
#pragma unroll
                for (int tn = 0; tn < 4; ++tn)
                    acc[tm][tn] = __builtin_amdgcn_mfma_f32_16x16x32_bf16(
                        af[tm], bfr[tn], acc[tm][tn], 0, 0, 0);
        }
        __syncthreads();
    }

    // C/D layout: col=lane&15, row=(lane>>4)*4+reg (m89-verified)
    if (OUTBF16) {
        float* scratch = (float*)smem_raw + wave * (16 * 68);
#pragma unroll
        for (int tm = 0; tm < 4; ++tm) {
            __syncthreads();
#pragma unroll
            for (int tn = 0; tn < 4; ++tn) {
                float bv = BIAS ? bias[n0 + wn + tn * 16 + lm] : 0.0f;
#pragma unroll
                for (int r = 0; r < 4; ++r) {
                    float v = acc[tm][tn][r] + bv;
                    if (RELU) v = fmaxf(v, 0.0f);
                    scratch[(q * 4 + r) * 68 + tn * 16 + lm] = v;
                }
            }
            __syncthreads();
#pragma unroll
            for (int p = 0; p < 2; ++p) {
                int row16 = (lane >> 3) + p * 8;
                int c0 = (lane & 7) * 8;
                float4 v0 = *(float4*)&scratch[row16 * 68 + c0];
                float4 v1 = *(float4*)&scratch[row16 * 68 + c0 + 4];
                bf16x8 o;
                o[0] = f2bf(v0.x); o[1] = f2bf(v0.y); o[2] = f2bf(v0.z); o[3] = f2bf(v0.w);
                o[4] = f2bf(v1.x); o[5] = f2bf(v1.y); o[6] = f2bf(v1.z); o[7] = f2bf(v1.w);
                int grow = m0 + wm + tm * 16 + row16;
                if (grow < M)
                    *(bf16x8*)((short*)C + (size_t)grow * N + n0 + wn + c0) = o;
            }
        }
    } else {
#pragma unroll
        for (int tm = 0; tm < 4; ++tm)
#pragma unroll
            for (int tn = 0; tn < 4; ++tn) {
                int col = n0 + wn + tn * 16 + lm;
#pragma unroll
                for (int r = 0; r < 4; ++r) {
                    int row = m0 + wm + tm * 16 + q * 4 + r;
                    if (row < M) {
                        float v = acc[tm][tn][r];
                        if (BIAS) v += bias[col];
                        if (RELU) v = fmaxf(v, 0.0f);
                        ((float*)C)[(size_t)row * N + col] = v;
                    }
                }
            }
    }
}

// ---------------------------------------------------------------------------
// Multi-job GEMM (up to 4 independent bf16-out jobs, flat 1-D grid).
// ---------------------------------------------------------------------------
struct GemmJobs {
    const short* A[4]; const short* Bt[4]; short* C[4];
    int M[4], N[4], K[4], lda[4], ldb[4];
    int cum[5];
};

__global__ __launch_bounds__(256, 4) void mfma_gemm_multi(GemmJobs jobs)
{
    __shared__ __align__(16) char smem_raw[32768];
    short* As = (short*)smem_raw;
    short* Bs = As + 128 * 64;

    int bid = blockIdx.x;
    int j = 0;
    while (bid >= jobs.cum[j + 1]) ++j;             // <=4, block-uniform
    int lt = bid - jobs.cum[j];
    const short* A  = jobs.A[j];
    const short* Bt = jobs.Bt[j];
    short* C = jobs.C[j];
    int M = jobs.M[j], N = jobs.N[j], K = jobs.K[j];
    int lda = jobs.lda[j], ldb = jobs.ldb[j];
    int ncols = N >> 7;
    int by = lt / ncols;
    int bx = lt - by * ncols;

    const int tid  = threadIdx.x;
    const int wave = tid >> 6;
    const int lane = tid & 63;
    const int m0 = by * 128;
    const int n0 = bx * 128;
    const int wm = (wave & 1) * 64;
    const int wn = (wave >> 1) * 64;

    f32x4 acc[4][4] = {};
    const int q  = lane >> 4;
    const int lm = lane & 15;

    for (int k0 = 0; k0 < K; k0 += 64) {
#pragma unroll
        for (int it = 0; it < 4; ++it) {
            int c    = (it & 1) * 256 + tid;
            int half = it >> 1;
            int row  = c >> 2;
            int kk   = (c & 3) * 8 + half * 32;
            int ldsc = half * 4096 + ((it & 1) * 256 + wave * 64) * 8;
            int gm = m0 + row; if (gm >= M) gm = M - 1;
            load16_lds(A + (size_t)gm * lda + k0 + kk, As + ldsc);
            load16_lds(Bt + (size_t)(n0 + row) * ldb + k0 + kk, Bs + ldsc);
        }
        __syncthreads();
#pragma unroll
        for (int half = 0; half < 2; ++half) {
            const short* Ah = As + half * 4096;
            const short* Bh = Bs + half * 4096;
            bf16x8 af[4], bfr[4];
#pragma unroll
            for (int t = 0; t < 4; ++t) {
                af[t]  = *(const bf16x8*)(Ah + (wm + t * 16 + lm) * 32 + q * 8);
                bfr[t] = *(const bf16x8*)(Bh + (wn + t * 16 + lm) * 32 + q * 8);
            }
#pragma unroll
            for (int tm = 0; tm < 4; ++tm)
#pragma unroll
                for (int tn = 0; tn < 4; ++tn)
                    acc[tm][tn] = __builtin_amdgcn_mfma_f32_16x16x32_bf16(
                        af[tm], bfr[tn], acc[tm][tn], 0, 0, 0);
        }
        __syncthreads();
    }

    float* scratch = (float*)smem_raw + wave * (16 * 68);
#pragma unroll
    for (int tm = 0; tm < 4; ++tm) {
        __syncthreads();
#pragma unroll
        for (int tn = 0; tn < 4; ++tn)
#pragma unroll
            for (int r = 0; r < 4; ++r)
                scratch[(q * 4 + r) * 68 + tn * 16 + lm] = acc[tm][tn][r];
        __syncthreads();
#pragma unroll
        for (int p = 0; p < 2; ++p) {
            int row16 = (lane >> 3) + p * 8;
            int c0 = (lane & 7) * 8;
            float4 v0 = *(float4*)&scratch[row16 * 68 + c0];
            float4 v1 = *(float4*)&scratch[row16 * 68 + c0 + 4];
            bf16x8 o;
            o[0] = f2bf(v0.x); o[1] = f2bf(v0.y); o[2] = f2bf(v0.z); o[3] = f2bf(v0.w);
            o[4] = f2bf(v1.x); o[5] = f2bf(v1.y); o[6] = f2bf(v1.z); o[7] = f2bf(v1.w);
            int grow = m0 + wm + tm * 16 + row16;
            if (grow < M)
                *(bf16x8*)(C + (size_t)grow * N + n0 + wn + c0) = o;
        }
    }
}

// ---------------------------------------------------------------------------
// UV merge (in-place): UVa = UVa + UVb + b1 (U-half cols only).
// ---------------------------------------------------------------------------
constexpr int N4UV = BSZ * NDET * 2048 / 4;   // 393216 short4s
__global__ __launch_bounds__(256) void uvmerge_kernel(
    short* __restrict__ UVa, const short* __restrict__ UVb,
    const float* __restrict__ b1)
{
    int i = blockIdx.x * 256 + threadIdx.x;
    if (i >= N4UV) return;
    short4 a = ((const short4*)UVa)[i];
    short4 b = ((const short4*)UVb)[i];
    int col4 = i & 511;
    float4 bb = {0.0f, 0.0f, 0.0f, 0.0f};
    if (col4 < 256) bb = ((const float4*)b1)[col4];
    short4 o;
    o.x = f2bf(bf2f(a.x) + bf2f(b.x) + bb.x);
    o.y = f2bf(bf2f(a.y) + bf2f(b.y) + bb.y);
    o.z = f2bf(bf2f(a.z) + bf2f(b.z) + bb.z);
    o.w = f2bf(bf2f(a.w) + bf2f(b.w) + bb.w);
    ((short4*)UVa)[i] = o;
}

// ---------------------------------------------------------------------------
// Fused pairs + rh: wave-per-row.
// ---------------------------------------------------------------------------
__global__ __launch_bounds__(256) void pairs_rh_kernel(
    const short* __restrict__ UVs,
    const int* __restrict__ sids, const int* __restrict__ oids,
    short* __restrict__ h1,
    const float* __restrict__ rp, const float* __restrict__ R1,
    const float* __restrict__ rb1, short* __restrict__ rh, int b0)
{
    int wave = threadIdx.x >> 6, lane = threadIdx.x & 63;
    int r = blockIdx.x * 4 + wave;
    int b = b0 + r / PAIRS;
    int p = r % PAIRS;

    const bf16x8* us = (const bf16x8*)(UVs + (size_t)(b * NDET + sids[p]) * 2048);
    const bf16x8* uo = (const bf16x8*)(UVs + (size_t)(b * NDET + oids[p]) * 2048 + 1024);
    bf16x8* hrow = (bf16x8*)(h1 + (size_t)r * DH);
#pragma unroll
    for (int i = 0; i < 2; ++i) {
        int idx = lane + i * 64;            // 128 bf16x8 per 1024-elem row
        bf16x8 a = us[idx], c = uo[idx];
        bf16x8 h;
#pragma unroll
        for (int e = 0; e < 8; ++e)
            h[e] = f2bf(fmaxf(bf2f(a[e]) + bf2f(c[e]), 0.0f));
        hrow[idx] = h;
    }

    int rg = b0 * PAIRS + r;
    const float* rowp = rp + (size_t)rg * 12;
    float4 acc = ((const float4*)rb1)[lane];
#pragma unroll
    for (int k = 0; k < 12; ++k) {
        float rv = rowp[k];
        float4 w = ((const float4*)(R1 + k * 256))[lane];
        acc.x = fmaf(rv, w.x, acc.x);
        acc.y = fmaf(rv, w.y, acc.y);
        acc.z = fmaf(rv, w.z, acc.z);
        acc.w = fmaf(rv, w.w, acc.w);
    }
    short4 o;
    o.x = f2bf(fmaxf(acc.x, 0.0f));
    o.y = f2bf(fmaxf(acc.y, 0.0f));
    o.z = f2bf(fmaxf(acc.z, 0.0f));
    o.w = f2bf(fmaxf(acc.w, 0.0f));
    ((short4*)(rh + (size_t)r * 256))[lane] = o;
}

// ---------------------------------------------------------------------------
// Fused row_prep + focal: wave-per-row (logits from extended GEMM columns;
// ||comb||^2 = 2 + 2*rho/(||so||*||re||)).
// ---------------------------------------------------------------------------
__global__ __launch_bounds__(256) void rowprep_focal_kernel(
    const short* __restrict__ so_ext, const short* __restrict__ re_ext,
    const float* __restrict__ traj, const float* __restrict__ temperature,
    const int* __restrict__ sids, const int* __restrict__ oids,
    const int* __restrict__ labels,
    float4* __restrict__ pn, float* __restrict__ dist_arr, int b0)
{
    int wave = threadIdx.x >> 6, lane = threadIdx.x & 63;
    int r = blockIdx.x * 4 + wave;
    int rg = b0 * PAIRS + r;
    int b = b0 + r / PAIRS;
    int p = r % PAIRS;

    const short* srow = so_ext + (size_t)r * NEXT;
    const short* rrow = re_ext + (size_t)r * NEXT;
    bf16x8 sv = *(const bf16x8*)(srow + lane * 8);
    bf16x8 uv = *(const bf16x8*)(rrow + lane * 8);
    float s[8], u[8];
#pragma unroll
    for (int i = 0; i < 8; ++i) { s[i] = bf2f(sv[i]); u[i] = bf2f(uv[i]); }

    const float* tsrc = (lane < 32)
        ? (traj + (size_t)(b * NDET + sids[p]) * EHALF + lane * 8)
        : (traj + (size_t)(b * NDET + oids[p]) * EHALF + (lane - 32) * 8);
    float4 t0 = ((const float4*)tsrc)[0], t1 = ((const float4*)tsrc)[1];
    float t[8] = {t0.x, t0.y, t0.z, t0.w, t1.x, t1.y, t1.z, t1.w};

    float ss = 0.0f, sr = 0.0f, rho = 0.0f, sd = 0.0f;
#pragma unroll
    for (int i = 0; i < 8; ++i) {
        ss  += s[i] * s[i];
        sr  += u[i] * u[i];
        rho += s[i] * u[i];
        sd  += fabsf(t[i] - s[i]);
    }
#pragma unroll
    for (int m = 1; m < 64; m <<= 1) {
        ss  += __shfl_xor(ss, m);
        sr  += __shfl_xor(sr, m);
        rho += __shfl_xor(rho, m);
        sd  += __shfl_xor(sd, m);
    }
    float inv_s = 1.0f / fmaxf(sqrtf(ss), 1e-12f);
    float inv_r = 1.0f / fmaxf(sqrtf(sr), 1e-12f);
    float ncomb = sqrtf(fmaxf(2.0f + 2.0f * rho * inv_s * inv_r, 0.0f));
    float scale = 1.0f / (fmaxf(ncomb, 1e-12f) * temperature[0]);

    float flp = 0.0f, fln = 0.0f, fm = 0.0f;
    size_t labbase = (size_t)rg * LABW;
#pragma unroll
    for (int h = 0; h < 2; ++h) {
        int c = lane + h * 64;
        if (c < NCLS) {
            float l = (bf2f(srow[DE + c]) * inv_s + bf2f(rrow[DE + c]) * inv_r) * scale;
            int tl = labels[labbase + 1 + c];
            if (tl > 0) fm = 1.0f;
            float tf = (float)tl;
            float pr = 1.0f / (1.0f + expf(-l));
            float lg = log1pf(expf(-fabsf(l)));
            float ce = fmaxf(l, 0.0f) - l * tf + lg;
            float pt = pr * tf + (1.0f - pr) * (1.0f - tf);
            float om = 1.0f - pt;
            float at = 0.25f * tf + 0.75f * (1.0f - tf);
            flp += at * ce * om * om;
            float ce0 = fmaxf(l, 0.0f) + lg;
            fln += 0.75f * ce0 * pr * pr;
        }
    }
#pragma unroll
    for (int m = 1; m < 64; m <<= 1) {
        flp += __shfl_xor(flp, m);
        fln += __shfl_xor(fln, m);
        fm  += __shfl_xor(fm, m);
    }
    if (lane == 0) {
        int posf = (fm > 0.5f) ? 1 : 0;
        int negf = (labels[labbase] > 0) ? 1 : 0;
        pn[rg] = make_float4(posf ? flp : 0.0f, negf ? fln : 0.0f, 0.0f,
                             (float)(posf + 2 * negf));
        dist_arr[rg] = sd;
    }
}

// ---------------------------------------------------------------------------
// Two-stage final reduce.
// ---------------------------------------------------------------------------
struct RedRec { double sp, sn, sd; int cp, cn; };
constexpr int RED1 = 64;
constexpr int ROWS_PER_RED = ROWS / RED1;           // 564

__global__ __launch_bounds__(256) void reduce1_kernel(
    const float4* __restrict__ pn, const float* __restrict__ dist_arr,
    RedRec* __restrict__ scratch)
{
    int tid = threadIdx.x;
    int base = blockIdx.x * ROWS_PER_RED;
    double sp = 0.0, sn = 0.0, sd = 0.0;
    int cp = 0, cn = 0;
    for (int i = tid; i < ROWS_PER_RED; i += 256) {
        float4 v = pn[base + i];
        sp += (double)v.x; sn += (double)v.y; sd += (double)dist_arr[base + i];
        int f = (int)v.w;
        cp += f & 1; cn += (f >> 1) & 1;
    }
    __shared__ double A[256], B[256], C[256];
    __shared__ int I[256], J[256];
    A[tid] = sp; B[tid] = sn; C[tid] = sd; I[tid] = cp; J[tid] = cn;
    __syncthreads();
    for (int st = 128; st > 0; st >>= 1) {
        if (tid < st) { A[tid] += A[tid + st]; B[tid] += B[tid + st]; C[tid] += C[tid + st];
                        I[tid] += I[tid + st]; J[tid] += J[tid + st]; }
        __syncthreads();
    }
    if (tid == 0) {
        RedRec rec; rec.sp = A[0]; rec.sn = B[0]; rec.sd = C[0];
        rec.cp = I[0]; rec.cn = J[0];
        scratch[blockIdx.x] = rec;
    }
}

__global__ __launch_bounds__(64) void reduce2_kernel(
    const RedRec* __restrict__ scratch, float* __restrict__ out)
{
    int lane = threadIdx.x;
    RedRec rec = scratch[lane];
    double sp = rec.sp, sn = rec.sn, sd = rec.sd;
    int cp = rec.cp, cn = rec.cn;
#pragma unroll
    for (int m = 1; m < 64; m <<= 1) {
        sp += __shfl_xor(sp, m);
        sn += __shfl_xor(sn, m);
        sd += __shfl_xor(sd, m);
        cp += __shfl_xor(cp, m);
        cn += __shfl_xor(cn, m);
    }
    if (lane == 0) {
        int cpv = cp < 1 ? 1 : cp;
        int cnv = cn < 1 ? 1 : cn;
        out[0] = (float)(sp / ((double)cpv * NCLS) +
                         sn / ((double)cnv * NCLS) +
                         sd / ((double)ROWS * DE));
    }
}

static inline int pad8(int x) { return (x + 7) & ~7; }

extern "C" void kernel_launch(void* const* d_in, const int* in_sizes, int n_in,
                              void* d_out, int out_size, void* d_ws, size_t ws_size,
                              hipStream_t stream)
{
    const float* det    = (const float*)d_in[0];
    const float* traj   = (const float*)d_in[1];
    const float* relpos = (const float*)d_in[2];
    const float* cw     = (const float*)d_in[3];
    const float* W1     = (const float*)d_in[4];
    const float* b1     = (const float*)d_in[5];
    const float* W2     = (const float*)d_in[6];
    const float* b2     = (const float*)d_in[7];
    const float* W3     = (const float*)d_in[8];
    const float* R1     = (const float*)d_in[9];
    const float* rb1    = (const float*)d_in[10];
    const float* R2     = (const float*)d_in[11];
    const float* temp   = (const float*)d_in[12];
    const int*   labels = (const int*)d_in[13];
    const int*   sids   = (const int*)d_in[14];
    const int*   oids   = (const int*)d_in[15];
    float* out = (float*)d_out;

    // ---- Workspace carve --------------------------------------------------
    char* ws = (char*)d_ws;
    size_t off = 0;
    auto carve = [&](size_t bytes) -> char* {
        char* p = ws + off;
        off = (off + bytes + 255) & ~(size_t)255;
        return p;
    };
    float4* pn       = (float4*)carve((size_t)ROWS * 16);
    float*  dist_arr = (float*)carve((size_t)ROWS * 4);
    short*  det_bf   = (short*)carve((size_t)BSZ * NDET * DF * 2);
    short*  W1t      = (short*)carve((size_t)2048 * 2048 * 2);
    short*  W2t      = (short*)carve((size_t)DH * DH * 2);
    short*  W3t      = (short*)carve((size_t)NEXT * DH * 2);      // [640][1024]
    short*  R2t      = (short*)carve((size_t)NEXT * 256 * 2);     // [640][256]
    short*  cwt      = (short*)carve((size_t)128 * DE * 2);
    short*  W3bf     = (short*)carve((size_t)DH * DE * 2);
    short*  R2bf     = (short*)carve((size_t)256 * DE * 2);
    short*  UVa      = (short*)carve((size_t)BSZ * NDET * 2048 * 2);
    short*  UVb      = (short*)carve((size_t)BSZ * NDET * 2048 * 2);
    RedRec* red_scratch = (RedRec*)carve((size_t)RED1 * sizeof(RedRec));
    size_t fixed_off = off;

    int b_ch = 1;
    for (int cand : {16, 8, 4, 2, 1}) {
        size_t rows  = (size_t)cand * PAIRS;
        size_t bytes = fixed_off + rows * 2048 + 256 + rows * 2048 + 256
                     + rows * 512 + 256 + rows * 1280 + 256;
        if (bytes <= ws_size) { b_ch = cand; break; }
    }
    const int chunk_rows = b_ch * PAIRS;
    const int n_chunks = BSZ / b_ch;
    char* reg1 = carve((size_t)chunk_rows * 2048);
    char* reg2 = carve((size_t)chunk_rows * 2048);
    char* reg3 = carve((size_t)chunk_rows * 512);
    char* reg4 = carve((size_t)chunk_rows * 1280);

    short* h1     = (short*)reg1;
    short* h2     = (short*)reg2;
    short* so_ext = (short*)reg1;     // overwrites h1 (dead after h2 GEMM)
    short* rh     = (short*)reg3;
    short* re_ext = (short*)reg4;     // own region (R10 race fix)

    // ---- Prep (1 launch) --------------------------------------------------
    TransJobs tj;
    tj.src[0] = W1;                    tj.dst[0] = W1t;                   tj.K[0] = DF;  tj.N[0] = DH;
    tj.src[1] = W1 + (size_t)DF * DH;  tj.dst[1] = W1t + (size_t)DH * DF; tj.K[1] = DF;  tj.N[1] = DH;
    tj.src[2] = W2;                    tj.dst[2] = W2t;                   tj.K[2] = DH;  tj.N[2] = DH;
    tj.src[3] = W3;                    tj.dst[3] = W3t;                   tj.K[3] = DH;  tj.N[3] = DE;
    tj.src[4] = R2;                    tj.dst[4] = R2t;                   tj.K[4] = 256; tj.N[4] = DE;
    tj.cum[0] = 0;
    for (int i = 0; i < 5; ++i)
        tj.cum[i + 1] = tj.cum[i] + (tj.K[i] / 32) * (tj.N[i] / 32);
    prep_kernel<<<NCONVB + tj.cum[5], 256, 0, stream>>>(
        det, det_bf, cw, cwt, W3, W3bf, R2, R2bf, tj);

    // One multi-job GEMM launch: UV split-K halves + classifier projections.
    GemmJobs gj;
    gj.A[0] = det_bf;        gj.Bt[0] = W1t;        gj.C[0] = UVa;
    gj.M[0] = BSZ * NDET;    gj.N[0] = 2048;        gj.K[0] = 1024;
    gj.lda[0] = 2048;        gj.ldb[0] = 2048;
    gj.A[1] = det_bf + 1024; gj.Bt[1] = W1t + 1024; gj.C[1] = UVb;
    gj.M[1] = BSZ * NDET;    gj.N[1] = 2048;        gj.K[1] = 1024;
    gj.lda[1] = 2048;        gj.ldb[1] = 2048;
    gj.A[2] = cwt;           gj.Bt[2] = W3bf;       gj.C[2] = W3t + (size_t)512 * DH;
    gj.M[2] = 128;           gj.N[2] = 1024;        gj.K[2] = 512;
    gj.lda[2] = 512;         gj.ldb[2] = 512;
    gj.A[3] = cwt;           gj.Bt[3] = R2bf;       gj.C[3] = R2t + (size_t)512 * 256;
    gj.M[3] = 128;           gj.N[3] = 256;         gj.K[3] = 512;
    gj.lda[3] = 512;         gj.ldb[3] = 512;
    gj.cum[0] = 0;
    for (int i = 0; i < 4; ++i)
        gj.cum[i + 1] = gj.cum[i] + (gj.N[i] / 128) * ((gj.M[i] + 127) / 128);
    mfma_gemm_multi<<<gj.cum[4], 256, 0, stream>>>(gj);   // 202 blocks

    // Merge: UVa += UVb + b1 (in-place)
    uvmerge_kernel<<<(N4UV + 255) / 256, 256, 0, stream>>>(UVa, UVb, b1);

    const int mg  = (chunk_rows + 127) / 128;
    const int mgp = pad8(mg);

    for (int c = 0; c < n_chunks; ++c) {
        int b0 = c * b_ch;

        pairs_rh_kernel<<<chunk_rows / 4, 256, 0, stream>>>(
            UVa, sids, oids, h1, relpos, R1, rb1, rh, b0);

        // h2 = bf16(relu(h1 @ W2 + b2))
        mfma_gemm<true, true, true, true, false>
            <<<dim3(DH / 128, mgp), 256, 0, stream>>>(
            h1, W2t, b2, h2, chunk_rows, DH, DH, DH, DH,
            nullptr, nullptr, nullptr, 0, 0, 0, 0, 0);

        // so_ext = bf16(h2 @ [W3 | W3·cw^T]) + re_ext = bf16(rh @ [R2 | R2·cw^T])
        mfma_gemm<false, false, true, true, true>
            <<<dim3(10, mgp), 256, 0, stream>>>(
            h2, W3t, nullptr, so_ext, chunk_rows, NEXT, DH, DH, DH,
            rh, R2t, re_ext, 5, 256, 256, 256, NEXT);

        rowprep_focal_kernel<<<chunk_rows / 4, 256, 0, stream>>>(
            so_ext, re_ext, traj, temp, sids, oids, labels, pn, dist_arr, b0);
    }

    reduce1_kernel<<<RED1, 256, 0, stream>>>(pn, dist_arr, red_scratch);
    reduce2_kernel<<<1, 64, 0, stream>>>(red_scratch, out);
}